// Round 8
// baseline (390.227 us; speedup 1.0000x reference)
//
#include <hip/hip_runtime.h>
#include <math.h>

#define H_DIM 1024
#define BATCH 512
#define NOBJ  64
#define M_TOT (NOBJ * BATCH)   // 32768 rows of the big GEMM
#define BK 64

typedef __attribute__((ext_vector_type(8))) _Float16 half8;  // 8 x f16 (4 VGPRs)
typedef __attribute__((ext_vector_type(4))) _Float16 half4;
typedef __attribute__((ext_vector_type(4))) float f32x4;     // MFMA acc

// global(16B) -> LDS direct, dest = wave-uniform base + lane*16
#define GLOAD16(gp, lp) \
    __builtin_amdgcn_global_load_lds( \
        (__attribute__((address_space(1))) const unsigned int*)(gp), \
        (__attribute__((address_space(3))) unsigned int*)(lp), 16, 0, 0)

__device__ __forceinline__ float fast_tanh(float x) {
    float e = __expf(2.0f * x);
    return 1.0f - __fdividef(2.0f, e + 1.0f);
}

// ---------------------------------------------------------------------------
// Mega-prep, ROLES FIRST so the long-chain k1 overlaps the kA flood:
//   bid <  256 : k0 — Wh[n][k] = f16(Wua[k][n]) (+ wsum at bid==0)
//   bid <  512 : k1 — d2 = h @ Wwa + ba  (fp32, 32x64 tiles, full K)
//   bid >= 512 : kA — A16 = f16(obj), 16 elems/thread
// ---------------------------------------------------------------------------
__global__ __launch_bounds__(256) void k_prep(const float* __restrict__ obj,
                                              _Float16* __restrict__ A16,
                                              const float* __restrict__ Wua,
                                              const float* __restrict__ Ww,
                                              _Float16* __restrict__ Wh,
                                              float* __restrict__ wsum,
                                              const float* __restrict__ hmat,
                                              const float* __restrict__ Wwa,
                                              const float* __restrict__ ba,
                                              float* __restrict__ d2) {
    __shared__ __align__(16) char smem[64 * 65 * 4];
    const int bid = blockIdx.x;
    const int tid = threadIdx.x;

    if (bid < 256) {
        // ---- k0: W_ua transpose+convert, 64x64 tile ----
        if (bid == 0) {
            for (int i = tid; i < H_DIM; i += 256)
                wsum[i] = Ww[i * 2] + Ww[i * 2 + 1];
        }
        float (*t)[65] = (float(*)[65])smem;
        const int k0 = (bid & 15) * 64, n0 = (bid >> 4) * 64;
        #pragma unroll
        for (int it = 0; it < 4; ++it) {
            int idx = it * 256 + tid;
            int kr = idx >> 4, nc = (idx & 15) * 4;
            *(float4*)&t[kr][nc] = *(const float4*)&Wua[(size_t)(k0 + kr) * H_DIM + n0 + nc];
        }
        __syncthreads();
        #pragma unroll
        for (int it = 0; it < 2; ++it) {
            int u = it * 256 + tid;
            int nr = u >> 3, ku = (u & 7) * 8;
            half8 w;
            #pragma unroll
            for (int j = 0; j < 8; ++j) w[j] = (_Float16)t[ku + j][nr];
            *(half8*)&Wh[(size_t)(n0 + nr) * H_DIM + k0 + ku] = w;
        }
        return;
    }

    if (bid < 512) {
        // ---- k1: d2 = h @ Wwa + ba ----
        const int b1 = bid - 256;                 // 0..255
        float (*As)[32] = (float(*)[32])smem;            // 4 KB
        float (*Ws)[64] = (float(*)[64])(smem + 4096);   // 8 KB
        const int m0 = (b1 & 15) * 32;
        const int n0 = (b1 >> 4) * 64;
        const int ty = tid >> 5;       // 0..7 -> rows ty*4..+3
        const int tx = tid & 31;       // 0..31 -> cols tx*2..+1
        float acc[4][2] = {};

        for (int k0 = 0; k0 < H_DIM; k0 += 32) {
            {   // stage A 32 rows x 32 k (transposed)
                int m = tid & 31, ks = tid >> 5;
                const float4 v = *(const float4*)&hmat[(size_t)(m0 + m) * H_DIM + k0 + ks * 4];
                As[ks * 4 + 0][m] = v.x;
                As[ks * 4 + 1][m] = v.y;
                As[ks * 4 + 2][m] = v.z;
                As[ks * 4 + 3][m] = v.w;
            }
            #pragma unroll
            for (int l = 0; l < 2; ++l) {   // stage W 32 k x 64 n
                int u = tid + l * 256;
                int n4 = u & 15, kk = u >> 4;
                *(float4*)&Ws[kk][n4 * 4] =
                    *(const float4*)&Wwa[(size_t)(k0 + kk) * H_DIM + n0 + n4 * 4];
            }
            __syncthreads();
            #pragma unroll
            for (int kk = 0; kk < 32; ++kk) {
                float av[4], bv[2];
                *(float4*)&av[0] = *(const float4*)&As[kk][ty * 4];
                bv[0] = Ws[kk][tx * 2];
                bv[1] = Ws[kk][tx * 2 + 1];
                #pragma unroll
                for (int i = 0; i < 4; ++i)
                    #pragma unroll
                    for (int j = 0; j < 2; ++j)
                        acc[i][j] += av[i] * bv[j];
            }
            __syncthreads();
        }
        #pragma unroll
        for (int i = 0; i < 4; ++i) {
            int rr = m0 + ty * 4 + i;
            #pragma unroll
            for (int j = 0; j < 2; ++j) {
                int c = n0 + tx * 2 + j;
                d2[(size_t)rr * H_DIM + c] = acc[i][j] + ba[c];
            }
        }
        return;
    }

    // ---- kA: obj -> A16 ----
    {
        const size_t i0 = ((size_t)(bid - 512) * 256 + tid) * 16;
        const float4 v0 = *(const float4*)&obj[i0];
        const float4 v1 = *(const float4*)&obj[i0 + 4];
        const float4 v2 = *(const float4*)&obj[i0 + 8];
        const float4 v3 = *(const float4*)&obj[i0 + 12];
        half8 w0, w1;
        w0[0] = (_Float16)v0.x; w0[1] = (_Float16)v0.y;
        w0[2] = (_Float16)v0.z; w0[3] = (_Float16)v0.w;
        w0[4] = (_Float16)v1.x; w0[5] = (_Float16)v1.y;
        w0[6] = (_Float16)v1.z; w0[7] = (_Float16)v1.w;
        w1[0] = (_Float16)v2.x; w1[1] = (_Float16)v2.y;
        w1[2] = (_Float16)v2.z; w1[3] = (_Float16)v2.w;
        w1[4] = (_Float16)v3.x; w1[5] = (_Float16)v3.y;
        w1[6] = (_Float16)v3.z; w1[7] = (_Float16)v3.w;
        *(half8*)&A16[i0]     = w0;
        *(half8*)&A16[i0 + 8] = w1;
    }
}

// ---------------------------------------------------------------------------
// Kernel 2 (main): fp16 MFMA GEMM fused tanh + row reduce.
// A: double-buffered global_load_lds (pre-swizzled source + swizzled ds_read,
//    0 bank conflicts). B: read fragments DIRECTLY from Wh (2 MB, L2-resident)
//    -> no Bsm, LDS 64.5->32.5 KB -> 4 blocks/CU (2x TLP), half the gloads
//    behind each barrier drain.
// Epilogue: wc0-half deposits to red[], wc1-half adds + stores (r6 race fix).
// ---------------------------------------------------------------------------
__global__ __launch_bounds__(256, 3) void k2_scores(const _Float16* __restrict__ A16,
                                                    const _Float16* __restrict__ Wh,
                                                    const float* __restrict__ d2,
                                                    const float* __restrict__ wsum,
                                                    float* __restrict__ sp) {
    __shared__ _Float16 Asm[2][128 * BK];   // 2 x 16 KB
    __shared__ float red[128];              // cross-wave (wc) row partials

    const int hw = blockIdx.x;           // 0..2047
    const int x  = hw & 7;               // XCD under round-robin dispatch
    const int j  = hw >> 3;              // 0..255 sequence within XCD
    const int m0 = (x * 32 + (j >> 3)) * 128;
    const int jn = j & 7;                // n-tile index
    const int n0 = jn * 128;
    const int tid  = threadIdx.x;
    const int lane = tid & 63;
    const int wid  = tid >> 6;           // 4 waves
    const int wr   = wid >> 1, wc = wid & 1;
    const int r    = lane & 15;
    const int g    = lane >> 4;

    // A staging sources (4 calls per thread, 8 rows each)
    const _Float16* aS[4];
    #pragma unroll
    for (int c = 0; c < 4; ++c) {
        const int row = wid * 32 + c * 8 + (lane >> 3);
        const int u   = lane & 7;
        const int us  = (u ^ (row & 7)) * 8;         // pre-swizzled 16B unit
        const int m   = m0 + row;
        aS[c] = A16 + ((size_t)(m & (BATCH - 1)) * NOBJ + (m >> 9)) * H_DIM + us;
    }
    // B fragment bases (global, L2-resident): row n0+wc*64+ni*16+r, col g*8
    const _Float16* bG[4];
    #pragma unroll
    for (int ni = 0; ni < 4; ++ni)
        bG[ni] = Wh + (size_t)(n0 + wc * 64 + ni * 16 + r) * H_DIM + g * 8;

    f32x4 acc[4][4];
    #pragma unroll
    for (int i = 0; i < 4; ++i)
        #pragma unroll
        for (int jj = 0; jj < 4; ++jj)
            acc[i][jj] = (f32x4){0.f, 0.f, 0.f, 0.f};

    // prologue: stage tile 0 into buf 0
    #pragma unroll
    for (int c = 0; c < 4; ++c)
        GLOAD16(aS[c], &Asm[0][(wid * 32 + c * 8) * 64]);
    __syncthreads();

    int cur = 0;
    #pragma unroll 1
    for (int t = 1; t < 16; ++t) {
        #pragma unroll
        for (int c = 0; c < 4; ++c)                  // issue next tile's loads
            GLOAD16(aS[c] + t * BK, &Asm[cur ^ 1][(wid * 32 + c * 8) * 64]);
        const int koff = (t - 1) * BK;
        #pragma unroll
        for (int s = 0; s < 2; ++s) {
            const int swz = ((s * 4 + g) ^ (r & 7)) * 8;
            half8 a[4], b[4];
            #pragma unroll
            for (int mi = 0; mi < 4; ++mi)
                a[mi] = *(const half8*)&Asm[cur][(wr * 64 + mi * 16 + r) * 64 + swz];
            #pragma unroll
            for (int ni = 0; ni < 4; ++ni)
                b[ni] = *(const half8*)&bG[ni][koff + s * 32];
            #pragma unroll
            for (int mi = 0; mi < 4; ++mi)
                #pragma unroll
                for (int ni = 0; ni < 4; ++ni)
                    acc[mi][ni] = __builtin_amdgcn_mfma_f32_16x16x32_f16(
                        a[mi], b[ni], acc[mi][ni], 0, 0, 0);
        }
        __syncthreads();   // vmcnt(0) drain lands here, after the MFMAs
        cur ^= 1;
    }
    {   // last tile
        const int koff = 15 * BK;
        #pragma unroll
        for (int s = 0; s < 2; ++s) {
            const int swz = ((s * 4 + g) ^ (r & 7)) * 8;
            half8 a[4], b[4];
            #pragma unroll
            for (int mi = 0; mi < 4; ++mi)
                a[mi] = *(const half8*)&Asm[cur][(wr * 64 + mi * 16 + r) * 64 + swz];
            #pragma unroll
            for (int ni = 0; ni < 4; ++ni)
                b[ni] = *(const half8*)&bG[ni][koff + s * 32];
            #pragma unroll
            for (int mi = 0; mi < 4; ++mi)
                #pragma unroll
                for (int ni = 0; ni < 4; ++ni)
                    acc[mi][ni] = __builtin_amdgcn_mfma_f32_16x16x32_f16(
                        a[mi], b[ni], acc[mi][ni], 0, 0, 0);
        }
    }

    // epilogue: tanh + weighted sum over this wave's 64 cols, combine halves.
    float wv[4];
    int   col[4];
    #pragma unroll
    for (int ni = 0; ni < 4; ++ni) {
        col[ni] = n0 + wc * 64 + ni * 16 + r;
        wv[ni]  = wsum[col[ni]];
    }
    float parts[4][4];
    #pragma unroll
    for (int mi = 0; mi < 4; ++mi) {
        #pragma unroll
        for (int reg = 0; reg < 4; ++reg) {
            const int row = m0 + wr * 64 + mi * 16 + g * 4 + reg;
            const int b   = row & (BATCH - 1);
            const float* d2b = d2 + (size_t)b * H_DIM;
            float part = 0.f;
            #pragma unroll
            for (int ni = 0; ni < 4; ++ni)
                part += fast_tanh(acc[mi][ni][reg] + d2b[col[ni]]) * wv[ni];
            part += __shfl_xor(part, 1);   // butterfly: all 16 lanes get sum
            part += __shfl_xor(part, 2);
            part += __shfl_xor(part, 4);
            part += __shfl_xor(part, 8);
            parts[mi][reg] = part;
        }
    }
    if (wc == 0 && r == 0) {
        #pragma unroll
        for (int mi = 0; mi < 4; ++mi)
            #pragma unroll
            for (int reg = 0; reg < 4; ++reg)
                red[wr * 64 + mi * 16 + g * 4 + reg] = parts[mi][reg];
    }
    __syncthreads();
    if (wc == 1 && r == 0) {
        #pragma unroll
        for (int mi = 0; mi < 4; ++mi)
            #pragma unroll
            for (int reg = 0; reg < 4; ++reg) {
                const int lr = wr * 64 + mi * 16 + g * 4 + reg;
                sp[(size_t)jn * M_TOT + m0 + lr] = parts[mi][reg] + red[lr];
            }
    }
}

// ---------------------------------------------------------------------------
// Kernel 3 (fast path): sum 8 partials -> softmax -> * zobj*10 -> weighted sum
// over A16. grid (512), 256 thr, 4 h-elems/thread.
// ---------------------------------------------------------------------------
__global__ __launch_bounds__(256) void k3_out16(const _Float16* __restrict__ A16,
                                                const float* __restrict__ sp,
                                                const float* __restrict__ zobj,
                                                float* __restrict__ out) {
    __shared__ float sc[NOBJ];
    __shared__ float al[NOBJ];
    const int b = blockIdx.x;
    const int tid = threadIdx.x;
    if (tid < NOBJ) {
        float s = 0.f;
        #pragma unroll
        for (int jn = 0; jn < 8; ++jn)
            s += sp[(size_t)jn * M_TOT + (size_t)tid * BATCH + b];
        sc[tid] = s;
    }
    __syncthreads();
    float mx = -1e30f;
    #pragma unroll 8
    for (int o = 0; o < NOBJ; ++o) mx = fmaxf(mx, sc[o]);
    float s = 0.f;
    #pragma unroll 8
    for (int o = 0; o < NOBJ; ++o) s += expf(sc[o] - mx);
    if (tid < NOBJ)
        al[tid] = expf(sc[tid] - mx) / s * zobj[(size_t)tid * BATCH + b] * 10.0f;
    __syncthreads();

    const int h0 = tid * 4;
    float a0 = 0, a1 = 0, a2 = 0, a3 = 0;
    const _Float16* base = A16 + (size_t)b * NOBJ * H_DIM + h0;
    #pragma unroll 8
    for (int o = 0; o < NOBJ; ++o) {
        float a = al[o];
        const half4 v = *(const half4*)&base[(size_t)o * H_DIM];
        a0 += a * (float)v[0]; a1 += a * (float)v[1];
        a2 += a * (float)v[2]; a3 += a * (float)v[3];
    }
    float4 o4 = {a0, a1, a2, a3};
    *(float4*)&out[(size_t)b * H_DIM + h0] = o4;
}

// ---------------------------------------------------------------------------
// FALLBACK path (ws too small for A16): reg-staged k2 + fp32 k3 (round-5).
// ---------------------------------------------------------------------------
__global__ __launch_bounds__(256) void k2_reg(const float* __restrict__ obj,
                                              const _Float16* __restrict__ Wh,
                                              const float* __restrict__ d2,
                                              const float* __restrict__ wsum,
                                              float* __restrict__ scores) {
    __shared__ _Float16 Asm[128 * BK];
    __shared__ _Float16 Bsm[128 * BK];
    const int hw = blockIdx.x;
    const int x  = hw & 7;
    const int j  = hw >> 3;
    const int m0 = (x * 32 + (j >> 3)) * 128;
    const int n0 = (j & 7) * 128;
    const int tid  = threadIdx.x;
    const int lane = tid & 63;
    const int wid  = tid >> 6;
    const int wr   = wid >> 1, wc = wid & 1;
    const int r    = lane & 15;
    const int g    = lane >> 4;
    const int srow = tid >> 3;
    const int su   = tid & 7;

    f32x4 acc[4][4];
    #pragma unroll
    for (int i = 0; i < 4; ++i)
        #pragma unroll
        for (int jj = 0; jj < 4; ++jj)
            acc[i][jj] = (f32x4){0.f, 0.f, 0.f, 0.f};

    for (int kk0 = 0; kk0 < H_DIM; kk0 += BK) {
        #pragma unroll
        for (int l = 0; l < 4; ++l) {
            const int row = l * 32 + srow;
            const int swz = (su ^ (row & 7)) * 8;
            {
                const int m = m0 + row;
                const size_t base = ((size_t)(m & (BATCH - 1)) * NOBJ + (m >> 9)) * H_DIM
                                    + kk0 + su * 8;
                const float4 v0 = *(const float4*)&obj[base];
                const float4 v1 = *(const float4*)&obj[base + 4];
                half8 w;
                w[0] = (_Float16)v0.x; w[1] = (_Float16)v0.y;
                w[2] = (_Float16)v0.z; w[3] = (_Float16)v0.w;
                w[4] = (_Float16)v1.x; w[5] = (_Float16)v1.y;
                w[6] = (_Float16)v1.z; w[7] = (_Float16)v1.w;
                *(half8*)&Asm[row * 64 + swz] = w;
            }
            {
                const half8 w = *(const half8*)&Wh[(size_t)(n0 + row) * H_DIM + kk0 + su * 8];
                *(half8*)&Bsm[row * 64 + swz] = w;
            }
        }
        __syncthreads();
        #pragma unroll
        for (int s = 0; s < 2; ++s) {
            const int swz = ((s * 4 + g) ^ (r & 7)) * 8;
            half8 a[4], b[4];
            #pragma unroll
            for (int mi = 0; mi < 4; ++mi)
                a[mi] = *(const half8*)&Asm[(wr * 64 + mi * 16 + r) * 64 + swz];
            #pragma unroll
            for (int ni = 0; ni < 4; ++ni)
                b[ni] = *(const half8*)&Bsm[(wc * 64 + ni * 16 + r) * 64 + swz];
            #pragma unroll
            for (int mi = 0; mi < 4; ++mi)
                #pragma unroll
                for (int ni = 0; ni < 4; ++ni)
                    acc[mi][ni] = __builtin_amdgcn_mfma_f32_16x16x32_f16(
                        a[mi], b[ni], acc[mi][ni], 0, 0, 0);
        }
        __syncthreads();
    }

    float wv[4];
    int   col[4];
    #pragma unroll
    for (int ni = 0; ni < 4; ++ni) {
        col[ni] = n0 + wc * 64 + ni * 16 + r;
        wv[ni]  = wsum[col[ni]];
    }
    #pragma unroll
    for (int mi = 0; mi < 4; ++mi) {
        #pragma unroll
        for (int reg = 0; reg < 4; ++reg) {
            const int row = m0 + wr * 64 + mi * 16 + g * 4 + reg;
            const int b   = row & (BATCH - 1);
            const float* d2b = d2 + (size_t)b * H_DIM;
            float part = 0.f;
            #pragma unroll
            for (int ni = 0; ni < 4; ++ni)
                part += fast_tanh(acc[mi][ni][reg] + d2b[col[ni]]) * wv[ni];
            part += __shfl_xor(part, 1);
            part += __shfl_xor(part, 2);
            part += __shfl_xor(part, 4);
            part += __shfl_xor(part, 8);
            if (r == 0) atomicAdd(&scores[row], part);
        }
    }
}

__global__ __launch_bounds__(128) void k3_out32(const float* __restrict__ obj,
                                                const float* __restrict__ scores,
                                                const float* __restrict__ zobj,
                                                float* __restrict__ out) {
    __shared__ float sc[NOBJ];
    __shared__ float al[NOBJ];
    const int b = blockIdx.x;
    const int tid = threadIdx.x;
    if (tid < NOBJ) sc[tid] = scores[(size_t)tid * BATCH + b];
    __syncthreads();
    float mx = -1e30f;
    #pragma unroll 8
    for (int o = 0; o < NOBJ; ++o) mx = fmaxf(mx, sc[o]);
    float s = 0.f;
    #pragma unroll 8
    for (int o = 0; o < NOBJ; ++o) s += expf(sc[o] - mx);
    if (tid < NOBJ)
        al[tid] = expf(sc[tid] - mx) / s * zobj[(size_t)tid * BATCH + b] * 10.0f;
    __syncthreads();

    const int h0 = (blockIdx.y * 128 + tid) * 4;
    float4 o4 = {0.f, 0.f, 0.f, 0.f};
    const float* base = obj + (size_t)b * NOBJ * H_DIM + h0;
    #pragma unroll 8
    for (int o = 0; o < NOBJ; ++o) {
        float a = al[o];
        float4 v = *(const float4*)&base[(size_t)o * H_DIM];
        o4.x += a * v.x;
        o4.y += a * v.y;
        o4.z += a * v.z;
        o4.w += a * v.w;
    }
    *(float4*)&out[(size_t)b * H_DIM + h0] = o4;
}

// ---------------------------------------------------------------------------
extern "C" void kernel_launch(void* const* d_in, const int* in_sizes, int n_in,
                              void* d_out, int out_size, void* d_ws, size_t ws_size,
                              hipStream_t stream) {
    const float* obj  = (const float*)d_in[0];  // (B, NOBJ, H)
    const float* hmat = (const float*)d_in[1];  // (1, B, H)
    const float* zobj = (const float*)d_in[2];  // (NOBJ, B)
    /* d_in[3] = t (unused) */
    const float* Ww   = (const float*)d_in[4];  // (H, 2)
    const float* Wua  = (const float*)d_in[5];  // (H, H)
    const float* ba   = (const float*)d_in[6];  // (H,)
    const float* Wwa  = (const float*)d_in[7];  // (H, H)
    float* out = (float*)d_out;

    char* ws = (char*)d_ws;
    const size_t d2_off   = 0;
    const size_t sp_off   = d2_off + (size_t)BATCH * H_DIM * 4;        // 2 MB
    const size_t wsum_off = sp_off + (size_t)8 * M_TOT * 4;            // +1 MB
    const size_t Wh_off   = wsum_off + 4096;                           // +4 KB
    const size_t A16_off  = Wh_off + (size_t)H_DIM * H_DIM * 2;        // +2 MB
    const size_t need     = A16_off + (size_t)M_TOT * H_DIM * 2;       // +64 MB

    float*    d2   = (float*)(ws + d2_off);
    float*    sp   = (float*)(ws + sp_off);
    float*    wsum = (float*)(ws + wsum_off);
    _Float16* Wh   = (_Float16*)(ws + Wh_off);
    _Float16* A16  = (_Float16*)(ws + A16_off);

    if (ws_size >= need) {
        k_prep<<<dim3(512 + 8192), 256, 0, stream>>>(obj, A16, Wua, Ww, Wh, wsum,
                                                     hmat, Wwa, ba, d2);
        k2_scores<<<dim3((M_TOT / 128) * (H_DIM / 128)), 256, 0, stream>>>(
            A16, Wh, d2, wsum, sp);
        k3_out16<<<dim3(BATCH), 256, 0, stream>>>(A16, sp, zobj, out);
    } else {
        hipMemsetAsync(sp, 0, (size_t)M_TOT * sizeof(float), stream);
        k_prep<<<dim3(512), 256, 0, stream>>>(obj, A16, Wua, Ww, Wh, wsum,
                                              hmat, Wwa, ba, d2);
        k2_reg<<<dim3((M_TOT / 128) * (H_DIM / 128)), 256, 0, stream>>>(
            obj, Wh, d2, wsum, sp);
        k3_out32<<<dim3(BATCH, 2), 128, 0, stream>>>(obj, sp, zobj, out);
    }
}

// Round 9
// 348.302 us; speedup vs baseline: 1.1204x; 1.1204x over previous
//
#include <hip/hip_runtime.h>
#include <math.h>

#define H_DIM 1024
#define BATCH 512
#define NOBJ  64
#define M_TOT (NOBJ * BATCH)   // 32768 rows of the big GEMM
#define BK 64

typedef __attribute__((ext_vector_type(8))) _Float16 half8;  // 8 x f16 (4 VGPRs)
typedef __attribute__((ext_vector_type(4))) _Float16 half4;
typedef __attribute__((ext_vector_type(4))) float f32x4;     // MFMA acc

// global(16B) -> LDS direct, dest = wave-uniform base + lane*16
#define GLOAD16(gp, lp) \
    __builtin_amdgcn_global_load_lds( \
        (__attribute__((address_space(1))) const unsigned int*)(gp), \
        (__attribute__((address_space(3))) unsigned int*)(lp), 16, 0, 0)

__device__ __forceinline__ float fast_tanh(float x) {
    float e = __expf(2.0f * x);
    return 1.0f - __fdividef(2.0f, e + 1.0f);
}

// ---------------------------------------------------------------------------
// Mega-prep, roles first, kA GRID-STRIDED (1024 blocks x 8 iters):
//   bid <  256 : k0 — Wh[n][k] = f16(Wua[k][n]) (+ wsum at bid==0)
//   bid <  512 : k1 — d2 = h @ Wwa + ba  (fp32, 32x64 tiles, full K)
//   bid >= 512 : kA — A16 = f16(obj), 16 elems/thread/iter, 8 iters
// ---------------------------------------------------------------------------
__global__ __launch_bounds__(256) void k_prep(const float* __restrict__ obj,
                                              _Float16* __restrict__ A16,
                                              const float* __restrict__ Wua,
                                              const float* __restrict__ Ww,
                                              _Float16* __restrict__ Wh,
                                              float* __restrict__ wsum,
                                              const float* __restrict__ hmat,
                                              const float* __restrict__ Wwa,
                                              const float* __restrict__ ba,
                                              float* __restrict__ d2) {
    __shared__ __align__(16) char smem[64 * 65 * 4];
    const int bid = blockIdx.x;
    const int tid = threadIdx.x;

    if (bid < 256) {
        // ---- k0: W_ua transpose+convert, 64x64 tile ----
        if (bid == 0) {
            for (int i = tid; i < H_DIM; i += 256)
                wsum[i] = Ww[i * 2] + Ww[i * 2 + 1];
        }
        float (*t)[65] = (float(*)[65])smem;
        const int k0 = (bid & 15) * 64, n0 = (bid >> 4) * 64;
        #pragma unroll
        for (int it = 0; it < 4; ++it) {
            int idx = it * 256 + tid;
            int kr = idx >> 4, nc = (idx & 15) * 4;
            *(float4*)&t[kr][nc] = *(const float4*)&Wua[(size_t)(k0 + kr) * H_DIM + n0 + nc];
        }
        __syncthreads();
        #pragma unroll
        for (int it = 0; it < 2; ++it) {
            int u = it * 256 + tid;
            int nr = u >> 3, ku = (u & 7) * 8;
            half8 w;
            #pragma unroll
            for (int j = 0; j < 8; ++j) w[j] = (_Float16)t[ku + j][nr];
            *(half8*)&Wh[(size_t)(n0 + nr) * H_DIM + k0 + ku] = w;
        }
        return;
    }

    if (bid < 512) {
        // ---- k1: d2 = h @ Wwa + ba ----
        const int b1 = bid - 256;                 // 0..255
        float (*As)[32] = (float(*)[32])smem;            // 4 KB
        float (*Ws)[64] = (float(*)[64])(smem + 4096);   // 8 KB
        const int m0 = (b1 & 15) * 32;
        const int n0 = (b1 >> 4) * 64;
        const int ty = tid >> 5;       // 0..7 -> rows ty*4..+3
        const int tx = tid & 31;       // 0..31 -> cols tx*2..+1
        float acc[4][2] = {};

        for (int k0 = 0; k0 < H_DIM; k0 += 32) {
            {   // stage A 32 rows x 32 k (transposed)
                int m = tid & 31, ks = tid >> 5;
                const float4 v = *(const float4*)&hmat[(size_t)(m0 + m) * H_DIM + k0 + ks * 4];
                As[ks * 4 + 0][m] = v.x;
                As[ks * 4 + 1][m] = v.y;
                As[ks * 4 + 2][m] = v.z;
                As[ks * 4 + 3][m] = v.w;
            }
            #pragma unroll
            for (int l = 0; l < 2; ++l) {   // stage W 32 k x 64 n
                int u = tid + l * 256;
                int n4 = u & 15, kk = u >> 4;
                *(float4*)&Ws[kk][n4 * 4] =
                    *(const float4*)&Wwa[(size_t)(k0 + kk) * H_DIM + n0 + n4 * 4];
            }
            __syncthreads();
            #pragma unroll
            for (int kk = 0; kk < 32; ++kk) {
                float av[4], bv[2];
                *(float4*)&av[0] = *(const float4*)&As[kk][ty * 4];
                bv[0] = Ws[kk][tx * 2];
                bv[1] = Ws[kk][tx * 2 + 1];
                #pragma unroll
                for (int i = 0; i < 4; ++i)
                    #pragma unroll
                    for (int j = 0; j < 2; ++j)
                        acc[i][j] += av[i] * bv[j];
            }
            __syncthreads();
        }
        #pragma unroll
        for (int i = 0; i < 4; ++i) {
            int rr = m0 + ty * 4 + i;
            #pragma unroll
            for (int j = 0; j < 2; ++j) {
                int c = n0 + tx * 2 + j;
                d2[(size_t)rr * H_DIM + c] = acc[i][j] + ba[c];
            }
        }
        return;
    }

    // ---- kA: obj -> A16, grid-stride (1024 blocks, 8 iters) ----
    {
        size_t i0 = ((size_t)(bid - 512) * 256 + tid) * 16;
        const size_t stride = (size_t)1024 * 256 * 16;   // 4,194,304 elems
        #pragma unroll 2
        for (int it = 0; it < 8; ++it, i0 += stride) {
            const float4 v0 = *(const float4*)&obj[i0];
            const float4 v1 = *(const float4*)&obj[i0 + 4];
            const float4 v2 = *(const float4*)&obj[i0 + 8];
            const float4 v3 = *(const float4*)&obj[i0 + 12];
            half8 w0, w1;
            w0[0] = (_Float16)v0.x; w0[1] = (_Float16)v0.y;
            w0[2] = (_Float16)v0.z; w0[3] = (_Float16)v0.w;
            w0[4] = (_Float16)v1.x; w0[5] = (_Float16)v1.y;
            w0[6] = (_Float16)v1.z; w0[7] = (_Float16)v1.w;
            w1[0] = (_Float16)v2.x; w1[1] = (_Float16)v2.y;
            w1[2] = (_Float16)v2.z; w1[3] = (_Float16)v2.w;
            w1[4] = (_Float16)v3.x; w1[5] = (_Float16)v3.y;
            w1[6] = (_Float16)v3.z; w1[7] = (_Float16)v3.w;
            *(half8*)&A16[i0]     = w0;
            *(half8*)&A16[i0 + 8] = w1;
        }
    }
}

// ---------------------------------------------------------------------------
// k2 inner tile: 2 sub-steps of K=32, 16 MFMA each half.
// ---------------------------------------------------------------------------
__device__ __forceinline__ void k2_tile(const _Float16* __restrict__ As_,
                                        const _Float16* __restrict__ Bs_,
                                        int wr, int wc, int r, int g,
                                        f32x4 acc[4][4]) {
    #pragma unroll
    for (int s = 0; s < 2; ++s) {
        const int swz = ((s * 4 + g) ^ (r & 7)) * 8;
        half8 a[4], b[4];
        #pragma unroll
        for (int mi = 0; mi < 4; ++mi)
            a[mi] = *(const half8*)&As_[(wr * 64 + mi * 16 + r) * 64 + swz];
        #pragma unroll
        for (int ni = 0; ni < 4; ++ni)
            b[ni] = *(const half8*)&Bs_[(wc * 64 + ni * 16 + r) * 64 + swz];
        #pragma unroll
        for (int mi = 0; mi < 4; ++mi)
            #pragma unroll
            for (int ni = 0; ni < 4; ++ni)
                acc[mi][ni] = __builtin_amdgcn_mfma_f32_16x16x32_f16(
                    a[mi], b[ni], acc[mi][ni], 0, 0, 0);
    }
}

// ---------------------------------------------------------------------------
// Kernel 2 (main, REVERTED to round-6/7 form — measured 117 µs):
// fp16 MFMA GEMM fused tanh + row reduce. Double-buffered global_load_lds for
// BOTH A and B (B-from-L2 experiment regressed: uncoalesced fragment reads on
// the MFMA dep chain). Pre-swizzled source + swizzled ds_read -> 0 conflicts.
// Epilogue: wc0-half deposits to red[], wc1-half adds + stores. No atomics.
// ---------------------------------------------------------------------------
__global__ __launch_bounds__(256) void k2_scores(const _Float16* __restrict__ A16,
                                                 const _Float16* __restrict__ Wh,
                                                 const float* __restrict__ d2,
                                                 const float* __restrict__ wsum,
                                                 float* __restrict__ sp) {
    __shared__ _Float16 Asm[2][128 * BK];   // 2 x 16 KB
    __shared__ _Float16 Bsm[2][128 * BK];   // 2 x 16 KB
    __shared__ float red[128];              // cross-wave (wc) row partials

    const int hw = blockIdx.x;           // 0..2047
    const int x  = hw & 7;               // XCD under round-robin dispatch
    const int j  = hw >> 3;              // 0..255 sequence within XCD
    const int m0 = (x * 32 + (j >> 3)) * 128;
    const int jn = j & 7;                // n-tile index
    const int n0 = jn * 128;
    const int tid  = threadIdx.x;
    const int lane = tid & 63;
    const int wid  = tid >> 6;           // 4 waves
    const int wr   = wid >> 1, wc = wid & 1;
    const int r    = lane & 15;
    const int g    = lane >> 4;

    // per-lane staging sources (4 A-calls + 4 B-calls per wave, 8 rows each)
    const _Float16* aS[4];
    const _Float16* bS[4];
    #pragma unroll
    for (int c = 0; c < 4; ++c) {
        const int row = wid * 32 + c * 8 + (lane >> 3);
        const int u   = lane & 7;
        const int us  = (u ^ (row & 7)) * 8;         // pre-swizzled 16B unit
        const int m   = m0 + row;
        aS[c] = A16 + ((size_t)(m & (BATCH - 1)) * NOBJ + (m >> 9)) * H_DIM + us;
        bS[c] = Wh + (size_t)(n0 + row) * H_DIM + us;
    }

    f32x4 acc[4][4];
    #pragma unroll
    for (int i = 0; i < 4; ++i)
        #pragma unroll
        for (int jj = 0; jj < 4; ++jj)
            acc[i][jj] = (f32x4){0.f, 0.f, 0.f, 0.f};

    // prologue: stage tile 0 into buf 0
    #pragma unroll
    for (int c = 0; c < 4; ++c) {
        GLOAD16(aS[c], &Asm[0][(wid * 32 + c * 8) * 64]);
        GLOAD16(bS[c], &Bsm[0][(wid * 32 + c * 8) * 64]);
    }
    __syncthreads();

    int cur = 0;
    for (int kk0 = BK; kk0 < H_DIM; kk0 += BK) {
        const int nxt = cur ^ 1;
        #pragma unroll
        for (int c = 0; c < 4; ++c) {                 // issue next tile's loads
            GLOAD16(aS[c] + kk0, &Asm[nxt][(wid * 32 + c * 8) * 64]);
            GLOAD16(bS[c] + kk0, &Bsm[nxt][(wid * 32 + c * 8) * 64]);
        }
        k2_tile(Asm[cur], Bsm[cur], wr, wc, r, g, acc);  // compute current
        __syncthreads();   // vmcnt(0) drain lands here, after the MFMAs
        cur = nxt;
    }
    k2_tile(Asm[cur], Bsm[cur], wr, wc, r, g, acc);

    // epilogue: tanh + weighted sum over this wave's 64 cols, combine halves.
    float wv[4];
    int   col[4];
    #pragma unroll
    for (int ni = 0; ni < 4; ++ni) {
        col[ni] = n0 + wc * 64 + ni * 16 + r;
        wv[ni]  = wsum[col[ni]];
    }
    float parts[4][4];
    #pragma unroll
    for (int mi = 0; mi < 4; ++mi) {
        #pragma unroll
        for (int reg = 0; reg < 4; ++reg) {
            const int row = m0 + wr * 64 + mi * 16 + g * 4 + reg;
            const int b   = row & (BATCH - 1);
            const float* d2b = d2 + (size_t)b * H_DIM;
            float part = 0.f;
            #pragma unroll
            for (int ni = 0; ni < 4; ++ni)
                part += fast_tanh(acc[mi][ni][reg] + d2b[col[ni]]) * wv[ni];
            part += __shfl_xor(part, 1);   // butterfly: all 16 lanes get sum
            part += __shfl_xor(part, 2);
            part += __shfl_xor(part, 4);
            part += __shfl_xor(part, 8);
            parts[mi][reg] = part;
        }
    }
    if (wc == 0 && r == 0) {
        #pragma unroll
        for (int mi = 0; mi < 4; ++mi)
            #pragma unroll
            for (int reg = 0; reg < 4; ++reg)
                red[wr * 64 + mi * 16 + g * 4 + reg] = parts[mi][reg];
    }
    __syncthreads();
    if (wc == 1 && r == 0) {
        #pragma unroll
        for (int mi = 0; mi < 4; ++mi)
            #pragma unroll
            for (int reg = 0; reg < 4; ++reg) {
                const int lr = wr * 64 + mi * 16 + g * 4 + reg;
                sp[(size_t)jn * M_TOT + m0 + lr] = parts[mi][reg] + red[lr];
            }
    }
}

// ---------------------------------------------------------------------------
// Kernel 3 (fast path): sum 8 partials -> softmax -> * zobj*10 -> weighted sum
// over A16. grid (512), 256 thr, 4 h-elems/thread.
// ---------------------------------------------------------------------------
__global__ __launch_bounds__(256) void k3_out16(const _Float16* __restrict__ A16,
                                                const float* __restrict__ sp,
                                                const float* __restrict__ zobj,
                                                float* __restrict__ out) {
    __shared__ float sc[NOBJ];
    __shared__ float al[NOBJ];
    const int b = blockIdx.x;
    const int tid = threadIdx.x;
    if (tid < NOBJ) {
        float s = 0.f;
        #pragma unroll
        for (int jn = 0; jn < 8; ++jn)
            s += sp[(size_t)jn * M_TOT + (size_t)tid * BATCH + b];
        sc[tid] = s;
    }
    __syncthreads();
    float mx = -1e30f;
    #pragma unroll 8
    for (int o = 0; o < NOBJ; ++o) mx = fmaxf(mx, sc[o]);
    float s = 0.f;
    #pragma unroll 8
    for (int o = 0; o < NOBJ; ++o) s += expf(sc[o] - mx);
    if (tid < NOBJ)
        al[tid] = expf(sc[tid] - mx) / s * zobj[(size_t)tid * BATCH + b] * 10.0f;
    __syncthreads();

    const int h0 = tid * 4;
    float a0 = 0, a1 = 0, a2 = 0, a3 = 0;
    const _Float16* base = A16 + (size_t)b * NOBJ * H_DIM + h0;
    #pragma unroll 8
    for (int o = 0; o < NOBJ; ++o) {
        float a = al[o];
        const half4 v = *(const half4*)&base[(size_t)o * H_DIM];
        a0 += a * (float)v[0]; a1 += a * (float)v[1];
        a2 += a * (float)v[2]; a3 += a * (float)v[3];
    }
    float4 o4 = {a0, a1, a2, a3};
    *(float4*)&out[(size_t)b * H_DIM + h0] = o4;
}

// ---------------------------------------------------------------------------
// FALLBACK path (ws too small for A16): reg-staged k2 + fp32 k3.
// ---------------------------------------------------------------------------
__global__ __launch_bounds__(256) void k2_reg(const float* __restrict__ obj,
                                              const _Float16* __restrict__ Wh,
                                              const float* __restrict__ d2,
                                              const float* __restrict__ wsum,
                                              float* __restrict__ scores) {
    __shared__ _Float16 Asm[128 * BK];
    __shared__ _Float16 Bsm[128 * BK];
    const int hw = blockIdx.x;
    const int x  = hw & 7;
    const int j  = hw >> 3;
    const int m0 = (x * 32 + (j >> 3)) * 128;
    const int n0 = (j & 7) * 128;
    const int tid  = threadIdx.x;
    const int lane = tid & 63;
    const int wid  = tid >> 6;
    const int wr   = wid >> 1, wc = wid & 1;
    const int r    = lane & 15;
    const int g    = lane >> 4;
    const int srow = tid >> 3;
    const int su   = tid & 7;

    f32x4 acc[4][4];
    #pragma unroll
    for (int i = 0; i < 4; ++i)
        #pragma unroll
        for (int jj = 0; jj < 4; ++jj)
            acc[i][jj] = (f32x4){0.f, 0.f, 0.f, 0.f};

    for (int kk0 = 0; kk0 < H_DIM; kk0 += BK) {
        #pragma unroll
        for (int l = 0; l < 4; ++l) {
            const int row = l * 32 + srow;
            const int swz = (su ^ (row & 7)) * 8;
            {
                const int m = m0 + row;
                const size_t base = ((size_t)(m & (BATCH - 1)) * NOBJ + (m >> 9)) * H_DIM
                                    + kk0 + su * 8;
                const float4 v0 = *(const float4*)&obj[base];
                const float4 v1 = *(const float4*)&obj[base + 4];
                half8 w;
                w[0] = (_Float16)v0.x; w[1] = (_Float16)v0.y;
                w[2] = (_Float16)v0.z; w[3] = (_Float16)v0.w;
                w[4] = (_Float16)v1.x; w[5] = (_Float16)v1.y;
                w[6] = (_Float16)v1.z; w[7] = (_Float16)v1.w;
                *(half8*)&Asm[row * 64 + swz] = w;
            }
            {
                const half8 w = *(const half8*)&Wh[(size_t)(n0 + row) * H_DIM + kk0 + su * 8];
                *(half8*)&Bsm[row * 64 + swz] = w;
            }
        }
        __syncthreads();
        k2_tile(Asm, Bsm, wr, wc, r, g, acc);
        __syncthreads();
    }

    float wv[4];
    int   col[4];
    #pragma unroll
    for (int ni = 0; ni < 4; ++ni) {
        col[ni] = n0 + wc * 64 + ni * 16 + r;
        wv[ni]  = wsum[col[ni]];
    }
    #pragma unroll
    for (int mi = 0; mi < 4; ++mi) {
        #pragma unroll
        for (int reg = 0; reg < 4; ++reg) {
            const int row = m0 + wr * 64 + mi * 16 + g * 4 + reg;
            const int b   = row & (BATCH - 1);
            const float* d2b = d2 + (size_t)b * H_DIM;
            float part = 0.f;
            #pragma unroll
            for (int ni = 0; ni < 4; ++ni)
                part += fast_tanh(acc[mi][ni][reg] + d2b[col[ni]]) * wv[ni];
            part += __shfl_xor(part, 1);
            part += __shfl_xor(part, 2);
            part += __shfl_xor(part, 4);
            part += __shfl_xor(part, 8);
            if (r == 0) atomicAdd(&scores[row], part);
        }
    }
}

__global__ __launch_bounds__(128) void k3_out32(const float* __restrict__ obj,
                                                const float* __restrict__ scores,
                                                const float* __restrict__ zobj,
                                                float* __restrict__ out) {
    __shared__ float sc[NOBJ];
    __shared__ float al[NOBJ];
    const int b = blockIdx.x;
    const int tid = threadIdx.x;
    if (tid < NOBJ) sc[tid] = scores[(size_t)tid * BATCH + b];
    __syncthreads();
    float mx = -1e30f;
    #pragma unroll 8
    for (int o = 0; o < NOBJ; ++o) mx = fmaxf(mx, sc[o]);
    float s = 0.f;
    #pragma unroll 8
    for (int o = 0; o < NOBJ; ++o) s += expf(sc[o] - mx);
    if (tid < NOBJ)
        al[tid] = expf(sc[tid] - mx) / s * zobj[(size_t)tid * BATCH + b] * 10.0f;
    __syncthreads();

    const int h0 = (blockIdx.y * 128 + tid) * 4;
    float4 o4 = {0.f, 0.f, 0.f, 0.f};
    const float* base = obj + (size_t)b * NOBJ * H_DIM + h0;
    #pragma unroll 8
    for (int o = 0; o < NOBJ; ++o) {
        float a = al[o];
        float4 v = *(const float4*)&base[(size_t)o * H_DIM];
        o4.x += a * v.x;
        o4.y += a * v.y;
        o4.z += a * v.z;
        o4.w += a * v.w;
    }
    *(float4*)&out[(size_t)b * H_DIM + h0] = o4;
}

// ---------------------------------------------------------------------------
extern "C" void kernel_launch(void* const* d_in, const int* in_sizes, int n_in,
                              void* d_out, int out_size, void* d_ws, size_t ws_size,
                              hipStream_t stream) {
    const float* obj  = (const float*)d_in[0];  // (B, NOBJ, H)
    const float* hmat = (const float*)d_in[1];  // (1, B, H)
    const float* zobj = (const float*)d_in[2];  // (NOBJ, B)
    /* d_in[3] = t (unused) */
    const float* Ww   = (const float*)d_in[4];  // (H, 2)
    const float* Wua  = (const float*)d_in[5];  // (H, H)
    const float* ba   = (const float*)d_in[6];  // (H,)
    const float* Wwa  = (const float*)d_in[7];  // (H, H)
    float* out = (float*)d_out;

    char* ws = (char*)d_ws;
    const size_t d2_off   = 0;
    const size_t sp_off   = d2_off + (size_t)BATCH * H_DIM * 4;        // 2 MB
    const size_t wsum_off = sp_off + (size_t)8 * M_TOT * 4;            // +1 MB
    const size_t Wh_off   = wsum_off + 4096;                           // +4 KB
    const size_t A16_off  = Wh_off + (size_t)H_DIM * H_DIM * 2;        // +2 MB
    const size_t need     = A16_off + (size_t)M_TOT * H_DIM * 2;       // +64 MB

    float*    d2   = (float*)(ws + d2_off);
    float*    sp   = (float*)(ws + sp_off);
    float*    wsum = (float*)(ws + wsum_off);
    _Float16* Wh   = (_Float16*)(ws + Wh_off);
    _Float16* A16  = (_Float16*)(ws + A16_off);

    if (ws_size >= need) {
        k_prep<<<dim3(512 + 1024), 256, 0, stream>>>(obj, A16, Wua, Ww, Wh, wsum,
                                                     hmat, Wwa, ba, d2);
        k2_scores<<<dim3((M_TOT / 128) * (H_DIM / 128)), 256, 0, stream>>>(
            A16, Wh, d2, wsum, sp);
        k3_out16<<<dim3(BATCH), 256, 0, stream>>>(A16, sp, zobj, out);
    } else {
        hipMemsetAsync(sp, 0, (size_t)M_TOT * sizeof(float), stream);
        k_prep<<<dim3(512), 256, 0, stream>>>(obj, A16, Wua, Ww, Wh, wsum,
                                              hmat, Wwa, ba, d2);
        k2_reg<<<dim3((M_TOT / 128) * (H_DIM / 128)), 256, 0, stream>>>(
            obj, Wh, d2, wsum, sp);
        k3_out32<<<dim3(BATCH, 2), 128, 0, stream>>>(obj, sp, zobj, out);
    }
}